// Round 9
// baseline (8210.299 us; speedup 1.0000x reference)
//
#include <hip/hip_runtime.h>

typedef unsigned short u16;
typedef unsigned int   u32;
typedef __attribute__((ext_vector_type(4))) float floatx4;
typedef __attribute__((ext_vector_type(4))) u32  u32x4;
typedef __attribute__((ext_vector_type(8))) short short8;

#define B_SZ  128
#define L_SEQ 1024
#define V_SZ  32
#define E_SZ  256
#define H_SZ  1024

#define N_GROUPS     8
#define WG_PER_GROUP 8                   // 8 WGs x 4 waves = 32 waves/group
#define N_BLOCKS     (N_GROUPS * WG_PER_GROUP)   // 64
#define LOGIT_BASE   (B_SZ * L_SEQ * V_SZ)

// workspace layout (bytes)
#define BAR_BYTES  8192
#define FLAG_OFF   (BAR_BYTES - 8)       // dtype flag
#define P_OFF      BAR_BYTES
#define P_BYTES    (V_SZ * H_SZ * 4)
#define HBUF_OFF   (P_OFF + P_BYTES)
#define NBUF       4                     // h_t lives in buf[t & 3]
#define HBUF_G     (NBUF * 16 * H_SZ)    // u16 elements per group
#define HBUF_BYTES (N_GROUPS * HBUF_G * 2)

// Sentinel dword = two bf16 NaNs. f2b(tanh(finite)) is in [-1,1] -> real h
// dwords are always < 0xFFFFFFFF.
#define SENT 0xFFFFFFFFu

#define MFMA16x16x32(a, b, c) __builtin_amdgcn_mfma_f32_16x16x32_bf16(a, b, c, 0, 0, 0)

__device__ inline float b2f(u16 u) {
    union { unsigned i; float f; } x; x.i = ((unsigned)u) << 16; return x.f;
}
__device__ inline u16 f2b(float f) {
    unsigned u = __float_as_uint(f);
    return (u16)((u + 0x7FFFu + ((u >> 16) & 1u)) >> 16);   // RNE
}
__device__ inline float ldf(const void* p, long i, int isf32) {
    return isf32 ? ((const float*)p)[i] : b2f(((const u16*)p)[i]);
}
__device__ inline u16 ldb(const void* p, long i, int isf32) {
    return isf32 ? f2b(((const float*)p)[i]) : ((const u16*)p)[i];
}

// tanh via hw exp2 + rcp: rel err ~1e-6, swamped by bf16 h-rounding (2^-8).
__device__ inline float fast_tanh(float x) {
    float cx = fminf(fmaxf(x, -15.f), 15.f);
    float t  = __builtin_amdgcn_exp2f(cx * 2.885390081777927f);   // e^{2x}
    return (t - 1.f) * __builtin_amdgcn_rcpf(t + 1.f);
}

// ---------------------------------------------------------------------------
// Protocol history (do not regress):
// R11/R12: sc0-only polling read stale data -> sc0+sc1 LLC-scope ONLY.
// R8: asm outputs must be early-clobber.
// R14/R15: incremental-MFMA-in-poll regressed -> keep the poll TIGHT.
// R16: fast_tanh + fused duty logits + cheap check -> 3216us. KEPT.
// R18: probe-then-bulk regressed -> detection and delivery share ONE RT.
// R19: lgkm-only barriers + backoff NEUTRAL -> chain is STRUCTURAL.
//
// R20/R21: BARRIER-FREE FULL-K WAVES. (R20 bench died to container failure;
// R21 = R20 + GLOBAL per-wave guard budget so ANY protocol stall terminates
// in ~tens of ms with visibly-wrong output instead of wedging the harness.)
// Each wave owns 32 h-columns x full K=1024 (same 64 MFMAs/step), produces
// final h in-register: no inter-wave reduce, NO BARRIERS in the loop.
// Epilogue transpose is in-wave via a private LDS tile (lgkmcnt-only).
// Logits: duty WAVE (w8 == (s-1)&31, 1-in-32 rotation), computed AFTER the
// h-store from the already-polled h_s A-frags, with Wo^T staged in LDS.
// Clear-safety (4-buffer rotation): wave's successful poll of FULL h_s =>
// all 32 producer waves stored h_s => all finished reading h_{s-1} =>
// clearing h_{s-1}'s buffer is sound. A fast wave at step s+1 cannot clear
// h_s's buffer while any wave still polls h_s, because its poll of h_{s+1}
// cannot succeed until that wave stores. Same-thread clear@s vs h-store@s+2
// (same addr): intervening step's poll vmcnt(0) drains the clear first.
// ---------------------------------------------------------------------------
__device__ inline void st_row16(u32* p, u32x4 d) {
    asm volatile("global_store_dwordx4 %0, %1, off sc0 sc1" :: "v"(p), "v"(d) : "memory");
}
__device__ inline u32 maxdw4(u32x4 a) {
    u32 m0 = a[0] > a[1] ? a[0] : a[1];
    u32 m1 = a[2] > a[3] ? a[2] : a[3];
    return m0 > m1 ? m0 : m1;
}
// 8 16B loads from base (+0..448), NO waitcnt (caller drains).
__device__ inline void ld8_nw(const u16* b, u32x4 a[8]) {
    u32x4 a0, a1, a2, a3, a4, a5, a6, a7;
    asm volatile(
        "global_load_dwordx4 %0, %8, off offset:0   sc0 sc1\n\t"
        "global_load_dwordx4 %1, %8, off offset:64  sc0 sc1\n\t"
        "global_load_dwordx4 %2, %8, off offset:128 sc0 sc1\n\t"
        "global_load_dwordx4 %3, %8, off offset:192 sc0 sc1\n\t"
        "global_load_dwordx4 %4, %8, off offset:256 sc0 sc1\n\t"
        "global_load_dwordx4 %5, %8, off offset:320 sc0 sc1\n\t"
        "global_load_dwordx4 %6, %8, off offset:384 sc0 sc1\n\t"
        "global_load_dwordx4 %7, %8, off offset:448 sc0 sc1"
        : "=&v"(a0), "=&v"(a1), "=&v"(a2), "=&v"(a3),
          "=&v"(a4), "=&v"(a5), "=&v"(a6), "=&v"(a7)
        : "v"(b)
        : "memory");
    a[0] = a0; a[1] = a1; a[2] = a2; a[3] = a3;
    a[4] = a4; a[5] = a5; a[6] = a6; a[7] = a7;
}
// Poll a wave's FULL-K A-frags (32 x 16B/lane): bulk load IS the detector
// (one LLC RT detects + delivers). Backoff only on the failure path.
// gbudget is a GLOBAL per-wave failed-pass budget (caps total spin time for
// the whole kernel run -> any protocol failure terminates fast & visibly).
__device__ inline void poll_row32(const u16* ab, u32x4 av[32], long& gbudget) {
    for (;;) {
        ld8_nw(ab,       av +  0);
        ld8_nw(ab + 256, av +  8);
        ld8_nw(ab + 512, av + 16);
        ld8_nw(ab + 768, av + 24);
        asm volatile("s_waitcnt vmcnt(0)" ::: "memory");
        u32 m = 0;
        #pragma unroll
        for (int j = 0; j < 32; ++j) { u32 t = maxdw4(av[j]); m = t > m ? t : m; }
        if (__all((int)(m != SENT))) return;
        if (--gbudget < 0) return;       // fail visibly + fast, never hang
        __builtin_amdgcn_s_sleep(2);
    }
}

// ---------------------------------------------------------------------------
__global__ void detect_dtype(const u16* __restrict__ emb, const int* __restrict__ xi,
                             int* __restrict__ flag) {
    float v = b2f(emb[threadIdx.x]);
    if (!(fabsf(v) <= 1.0e6f)) atomicOr(flag, 1);
    if (xi[2 * threadIdx.x + 1] != 0) atomicOr(flag, 2);
}

__global__ void precompute_P(const void* __restrict__ emb, const void* __restrict__ We,
                             const void* __restrict__ bh, float* __restrict__ P,
                             const int* __restrict__ flag) {
    const int isf32 = *flag & 1;
    int o = blockIdx.x * 256 + threadIdx.x;
    int v = o >> 10, h = o & (H_SZ - 1);
    float acc = ldf(bh, h, isf32);
    for (int e = 0; e < E_SZ; ++e)
        acc += ldf(emb, v * E_SZ + e, isf32) * ldf(We, (long)e * H_SZ + h, isf32);
    P[o] = acc;
}

// ---------------------------------------------------------------------------
// Persistent RNN — R21. 64 WGs x 256 thr; group g=blockIdx&7 (16 batches).
// Group-wave w8 = (blockIdx>>3)*4 + wave owns cols [32*w8, 32*w8+32) x full
// K: whf[2][32] stationary (256 VGPR), 64 MFMAs/step in 4 indep chains,
// in-wave LDS transpose, fast-tanh, one 16B h-store. NO barriers in loop.
// ---------------------------------------------------------------------------
__global__ void __launch_bounds__(256, 1) rnn_kernel(
    const void* __restrict__ xp, const void* __restrict__ hidden,
    const void* __restrict__ Wh, const void* __restrict__ Wo,
    const void* __restrict__ bo, const float* __restrict__ P,
    u16* __restrict__ hbuf, float* __restrict__ out,
    const int* __restrict__ flag)
{
    __shared__ __align__(16) u16  woT[V_SZ][H_SZ + 8];   // Wo^T, pad 8 u16 (66.0 KB)
    __shared__ __align__(16) float trb[4][16][33];       // per-wave transpose (8.4 KB)

    const int fl    = *flag;
    const int isf32 = fl & 1;
    const int xi64  = !(fl & 2);
    const int g     = blockIdx.x & 7;
    const int wg    = blockIdx.x >> 3;
    const int b0    = g * 16;
    const int tid   = threadIdx.x;
    const int wave  = tid >> 6;
    const int lane  = tid & 63;
    const int lrow  = lane & 15;
    const int quad  = lane >> 4;
    const int w8    = wg * 4 + wave;      // group-wave id 0..31
    const int wcol0 = w8 * 32;            // owned 32-col slice

    const int* x32       = (const int*)xp;
    const long long* x64 = (const long long*)xp;
    u16* hb = hbuf + g * HBUF_G;          // 4 rotating buffers of 16 x H bf16

    long gbudget = 100000L;               // global failed-pass budget/wave

    // ---- stage Wo^T into LDS (read by duty waves only) ----
    for (int i = tid; i < V_SZ * H_SZ; i += 256) {
        int k = i >> 5, v = i & 31;
        woT[v][k] = ldb(Wo, (long)k * V_SZ + v, isf32);
    }

    // ---- stationary Wh B-frags: cols {wcol0+lrow, wcol0+16+lrow}, full K ----
    short8 whf[2][32];
    #pragma unroll
    for (int c = 0; c < 32; ++c) {
        const int kb = c * 32 + quad * 8;
        #pragma unroll
        for (int j = 0; j < 8; ++j) {
            whf[0][c][j] = (short)ldb(Wh, (long)(kb + j) * H_SZ + wcol0 + lrow,      isf32);
            whf[1][c][j] = (short)ldb(Wh, (long)(kb + j) * H_SZ + wcol0 + 16 + lrow, isf32);
        }
    }

    const float bov0 = ldf(bo, lrow,      isf32);
    const float bov1 = ldf(bo, 16 + lrow, isf32);

    // ---- h_0: store own slice into buf0 (buf1..3 sentinel via host memset).
    //      No sync needed: step-0 polls wait for all 32 waves' h_0 stores. ----
    {
        u32x4 d;
        #pragma unroll
        for (int p = 0; p < 4; ++p) {
            u16 lo = ldb(hidden, (long)(b0 + lrow) * H_SZ + wcol0 + quad * 8 + 2 * p,     isf32);
            u16 hi = ldb(hidden, (long)(b0 + lrow) * H_SZ + wcol0 + quad * 8 + 2 * p + 1, isf32);
            d[p] = (u32)lo | ((u32)hi << 16);
        }
        st_row16((u32*)(hb + lrow * H_SZ + wcol0 + quad * 8), d);
    }
    __syncthreads();   // Wo^T staged (only barrier; outside the loop)

    for (int s = 0; s < L_SEQ; ++s) {
        const u16* hc = hb + (s & 3) * (16 * H_SZ);          // h_s
        u16* hn       = hb + ((s + 1) & 3) * (16 * H_SZ);    // h_{s+1}
        u16* hcl      = hb + ((s + 3) & 3) * (16 * H_SZ);    // holds h_{s-1}
        const int dol = (s >= 1) & (w8 == ((s - 1) & 31));   // duty wave

        // ---- x/P prefetch (independent of h; rides under the poll) ----
        long xoff = (long)(b0 + lrow) * L_SEQ + s;
        int xv = xi64 ? (int)x64[xoff] : x32[xoff];
        const floatx4* pp = (const floatx4*)(P + (long)xv * H_SZ + wcol0 + quad * 8);
        floatx4 pv0 = pp[0], pv1 = pp[1];

        // ---- poll FULL-K A-frags: one RT detects + delivers h_s ----
        u32x4 av[32];
        poll_row32(hc + lrow * H_SZ + quad * 8, av, gbudget);

        // ---- re-sentinel own slice of h_{s-1}'s buffer (poll certified) ----
        if (s <= L_SEQ - 3) {
            u32x4 f = { SENT, SENT, SENT, SENT };
            st_row16((u32*)(hcl + lrow * H_SZ + wcol0 + quad * 8), f);
        }

        // ---- 64 MFMAs, 4 independent chains (full dep-hiding) ----
        floatx4 aA0 = {0,0,0,0}, aB0 = {0,0,0,0}, aA1 = {0,0,0,0}, aB1 = {0,0,0,0};
        #pragma unroll
        for (int c = 0; c < 32; c += 2) {
            union { u32x4 v; short8 h; } u0, u1;
            u0.v = av[c]; u1.v = av[c + 1];
            aA0 = MFMA16x16x32(u0.h, whf[0][c],     aA0);
            aA1 = MFMA16x16x32(u0.h, whf[1][c],     aA1);
            aB0 = MFMA16x16x32(u1.h, whf[0][c + 1], aB0);
            aB1 = MFMA16x16x32(u1.h, whf[1][c + 1], aB1);
        }
        floatx4 ac0 = aA0 + aB0, ac1 = aA1 + aB1;

        // ---- in-wave transpose (C-layout -> row-major) via private LDS ----
        #pragma unroll
        for (int r = 0; r < 4; ++r) {
            trb[wave][quad * 4 + r][lrow]      = ac0[r];
            trb[wave][quad * 4 + r][16 + lrow] = ac1[r];
        }
        asm volatile("s_waitcnt lgkmcnt(0)" ::: "memory");
        __builtin_amdgcn_sched_barrier(0);

        // ---- epilogue: h = tanh(P + acc); one 16B bf16 store ----
        float hv[8];
        #pragma unroll
        for (int j = 0; j < 4; ++j) hv[j]     = fast_tanh(trb[wave][lrow][quad * 8 + j]     + pv0[j]);
        #pragma unroll
        for (int j = 0; j < 4; ++j) hv[4 + j] = fast_tanh(trb[wave][lrow][quad * 8 + 4 + j] + pv1[j]);
        u32x4 d;
        #pragma unroll
        for (int p = 0; p < 4; ++p)
            d[p] = (u32)f2b(hv[2 * p]) | ((u32)f2b(hv[2 * p + 1]) << 16);
        st_row16((u32*)(hn + lrow * H_SZ + wcol0 + quad * 8), d);
        if (s == L_SEQ - 1) {
            float* op = out + LOGIT_BASE + (long)(b0 + lrow) * H_SZ + wcol0 + quad * 8;
            ((floatx4*)op)[0] = floatx4{hv[0], hv[1], hv[2], hv[3]};
            ((floatx4*)op)[1] = floatx4{hv[4], hv[5], hv[6], hv[7]};
        }

        // ---- duty wave: logits[s-1] = h_s @ Wo from av (off the h chain) ----
        if (dol) {
            floatx4 L0 = {0,0,0,0}, L1 = {0,0,0,0};
            #pragma unroll
            for (int c = 0; c < 32; ++c) {
                union { u32x4 v; short8 h; } ua; ua.v = av[c];
                short8 w0 = *(const short8*)&woT[lrow][c * 32 + quad * 8];
                short8 w1 = *(const short8*)&woT[16 + lrow][c * 32 + quad * 8];
                L0 = MFMA16x16x32(ua.h, w0, L0);
                L1 = MFMA16x16x32(ua.h, w1, L1);
            }
            #pragma unroll
            for (int r = 0; r < 4; ++r) {
                long ob = ((long)(b0 + quad * 4 + r) * L_SEQ + (s - 1)) * V_SZ;
                out[ob + lrow]      = L0[r] + bov0;
                out[ob + 16 + lrow] = L1[r] + bov1;
            }
        }
    }

    // ---- logits[L-1] from h_L (buf[1024&3] = buf0): group-wave 31 ----
    if (w8 == 31) {
        u32x4 av[32];
        poll_row32(hb + lrow * H_SZ + quad * 8, av, gbudget);
        floatx4 L0 = {0,0,0,0}, L1 = {0,0,0,0};
        #pragma unroll
        for (int c = 0; c < 32; ++c) {
            union { u32x4 v; short8 h; } ua; ua.v = av[c];
            short8 w0 = *(const short8*)&woT[lrow][c * 32 + quad * 8];
            short8 w1 = *(const short8*)&woT[16 + lrow][c * 32 + quad * 8];
            L0 = MFMA16x16x32(ua.h, w0, L0);
            L1 = MFMA16x16x32(ua.h, w1, L1);
        }
        #pragma unroll
        for (int r = 0; r < 4; ++r) {
            long ob = ((long)(b0 + quad * 4 + r) * L_SEQ + (L_SEQ - 1)) * V_SZ;
            out[ob + lrow]      = L0[r] + bov0;
            out[ob + 16 + lrow] = L1[r] + bov1;
        }
    }
}

// ---------------------------------------------------------------------------
extern "C" void kernel_launch(void* const* d_in, const int* in_sizes, int n_in,
                              void* d_out, int out_size, void* d_ws, size_t ws_size,
                              hipStream_t stream) {
    (void)in_sizes; (void)n_in; (void)out_size; (void)ws_size;
    const void* x      = d_in[0];
    const void* hidden = d_in[1];
    const void* emb    = d_in[2];
    const void* We     = d_in[3];
    const void* Wh     = d_in[4];
    const void* bh     = d_in[5];
    const void* Wo     = d_in[6];
    const void* bo     = d_in[7];
    float* out = (float*)d_out;

    char* ws = (char*)d_ws;
    int*   flag = (int*)(ws + FLAG_OFF);
    float* P    = (float*)(ws + P_OFF);
    u16*   hbuf = (u16*)(ws + HBUF_OFF);

    hipMemsetAsync(ws, 0, BAR_BYTES, stream);                 // dtype flag = 0
    hipMemsetAsync(ws + HBUF_OFF, 0xFF, HBUF_BYTES, stream);  // all h-bufs = sentinel

    detect_dtype<<<dim3(1), dim3(256), 0, stream>>>((const u16*)emb, (const int*)x, flag);
    precompute_P<<<dim3(128), dim3(256), 0, stream>>>(emb, We, bh, P, flag);

    rnn_kernel<<<dim3(N_BLOCKS), dim3(256), 0, stream>>>(
        x, hidden, Wh, Wo, bo, P, hbuf, out, flag);
}

// Round 11
// 3392.514 us; speedup vs baseline: 2.4201x; 2.4201x over previous
//
#include <hip/hip_runtime.h>

typedef unsigned short u16;
typedef unsigned int   u32;
typedef __attribute__((ext_vector_type(4))) float floatx4;
typedef __attribute__((ext_vector_type(4))) u32  u32x4;
typedef __attribute__((ext_vector_type(8))) short short8;

#define B_SZ  128
#define L_SEQ 1024
#define V_SZ  32
#define E_SZ  256
#define H_SZ  1024

#define N_GROUPS     8
#define WG_PER_GROUP 8                   // 8 WGs x 128 cols = 1024
#define N_BLOCKS     (N_GROUPS * WG_PER_GROUP)   // 64
#define LOGIT_BASE   (B_SZ * L_SEQ * V_SZ)

// workspace layout (bytes)
#define BAR_BYTES  8192
#define FLAG_OFF   (BAR_BYTES - 8)       // dtype flag
#define P_OFF      BAR_BYTES
#define P_BYTES    (V_SZ * H_SZ * 4)
#define HBUF_OFF   (P_OFF + P_BYTES)
#define NBUF       4                     // h_t lives in buf[t & 3]
#define HBUF_G     (NBUF * 16 * H_SZ)    // u16 elements per group
#define HBUF_BYTES (N_GROUPS * HBUF_G * 2)

// Sentinel dword = two bf16 NaNs. f2b(tanh(finite)) is in [-1,1] -> real h
// dwords are always < 0xFFFFFFFF, so freshness("all !=SENT") == max != SENT.
#define SENT 0xFFFFFFFFu

#define MFMA16x16x32(a, b, c) __builtin_amdgcn_mfma_f32_16x16x32_bf16(a, b, c, 0, 0, 0)

__device__ inline float b2f(u16 u) {
    union { unsigned i; float f; } x; x.i = ((unsigned)u) << 16; return x.f;
}
__device__ inline u16 f2b(float f) {
    unsigned u = __float_as_uint(f);
    return (u16)((u + 0x7FFFu + ((u >> 16) & 1u)) >> 16);   // RNE
}
__device__ inline float ldf(const void* p, long i, int isf32) {
    return isf32 ? ((const float*)p)[i] : b2f(((const u16*)p)[i]);
}
__device__ inline u16 ldb(const void* p, long i, int isf32) {
    return isf32 ? f2b(((const float*)p)[i]) : ((const u16*)p)[i];
}

// tanh via hw exp2 + rcp: rel err ~1e-6, swamped by bf16 h-rounding (2^-8).
__device__ inline float fast_tanh(float x) {
    float cx = fminf(fmaxf(x, -15.f), 15.f);
    float t  = __builtin_amdgcn_exp2f(cx * 2.885390081777927f);   // e^{2x}
    return (t - 1.f) * __builtin_amdgcn_rcpf(t + 1.f);
}

// ---------------------------------------------------------------------------
// Protocol history (do not regress):
// R11/R12: sc0-only polling read stale data -> sc0+sc1 LLC-scope ONLY.
// R8:  asm outputs must be early-clobber.
// R14/R15: incremental-MFMA-in-poll regressed -> keep the poll TIGHT.
// R16: fast_tanh + fused duty logits + cheap check -> 3151us steady. BASE.
// R18: probe-then-bulk regressed -> detection and delivery share ONE RT.
// R19: lgkm-only barriers + backoff NEUTRAL -> residual = detection phase.
// R21: full-K waves regressed 2.6x -> keep per-wave fan-in small.
// R22: CRASHED - rule #18: bare waitcnt asm does NOT order REGISTER reads;
//      xr read hoisted above VMCNT0 -> wild P address -> memory fault.
//      Lesson: completion waits live IN the load asm block, or are fenced
//      with __builtin_amdgcn_sched_barrier(0) immediately after.
//
// R23 (this round), base = R19:
// CROSS-STEP SPECULATIVE PIPELINE. At step end (after all stores, before
// sync-B) issue with NO wait: S0 <- h-snapshot @ next buffer, pu <- P[x_{s+1}]
// (address from xr, completed at this step's head), xr <- x_{s+2}.
// At step head: ONE VMCNT0 (drains loads issued a full epilogue+barrier ago
// -> nearly free) + sched_barrier(0) fence, then check S0. Hit => zero
// consumer-side serial RT (h, P, x already in regs). Miss => R19's exact
// self-contained poll (waitcnt in-block) reusing S0 regs (safe: head drain
// retired them). Register ping-pong (S0/pu/xr read-then-reissue) audited.
// Buffer-rotation / clear-safety proof unchanged from R13 (see history).
// ---------------------------------------------------------------------------
#define VMCNT0() asm volatile("s_waitcnt vmcnt(0)" ::: "memory")

__device__ inline void bar_lgkm() {
    asm volatile("s_waitcnt lgkmcnt(0)" ::: "memory");   // LDS writes visible
    __builtin_amdgcn_s_barrier();
    asm volatile("" ::: "memory");                       // no hoist across
}
__device__ inline void st_row16(u32* p, u32x4 d) {
    asm volatile("global_store_dwordx4 %0, %1, off sc0 sc1" :: "v"(p), "v"(d) : "memory");
}
// 8 16B loads, waitcnt IN-BLOCK (outputs complete at block end; R13-R19 proven).
__device__ inline void ld_row16_raw(const u16* abase, u32x4 a[8]) {
    u32x4 a0, a1, a2, a3, a4, a5, a6, a7;
    asm volatile(
        "global_load_dwordx4 %0, %8, off offset:0   sc0 sc1\n\t"
        "global_load_dwordx4 %1, %8, off offset:64  sc0 sc1\n\t"
        "global_load_dwordx4 %2, %8, off offset:128 sc0 sc1\n\t"
        "global_load_dwordx4 %3, %8, off offset:192 sc0 sc1\n\t"
        "global_load_dwordx4 %4, %8, off offset:256 sc0 sc1\n\t"
        "global_load_dwordx4 %5, %8, off offset:320 sc0 sc1\n\t"
        "global_load_dwordx4 %6, %8, off offset:384 sc0 sc1\n\t"
        "global_load_dwordx4 %7, %8, off offset:448 sc0 sc1\n\t"
        "s_waitcnt vmcnt(0)"
        : "=&v"(a0), "=&v"(a1), "=&v"(a2), "=&v"(a3),
          "=&v"(a4), "=&v"(a5), "=&v"(a6), "=&v"(a7)
        : "v"(abase)
        : "memory");
    a[0] = a0; a[1] = a1; a[2] = a2; a[3] = a3;
    a[4] = a4; a[5] = a5; a[6] = a6; a[7] = a7;
}
// 8 16B loads, NO wait (speculative issue; completed by next head VMCNT0).
__device__ inline void ld8_nw(const u16* b, u32x4 a[8]) {
    u32x4 a0, a1, a2, a3, a4, a5, a6, a7;
    asm volatile(
        "global_load_dwordx4 %0, %8, off offset:0   sc0 sc1\n\t"
        "global_load_dwordx4 %1, %8, off offset:64  sc0 sc1\n\t"
        "global_load_dwordx4 %2, %8, off offset:128 sc0 sc1\n\t"
        "global_load_dwordx4 %3, %8, off offset:192 sc0 sc1\n\t"
        "global_load_dwordx4 %4, %8, off offset:256 sc0 sc1\n\t"
        "global_load_dwordx4 %5, %8, off offset:320 sc0 sc1\n\t"
        "global_load_dwordx4 %6, %8, off offset:384 sc0 sc1\n\t"
        "global_load_dwordx4 %7, %8, off offset:448 sc0 sc1"
        : "=&v"(a0), "=&v"(a1), "=&v"(a2), "=&v"(a3),
          "=&v"(a4), "=&v"(a5), "=&v"(a6), "=&v"(a7)
        : "v"(b)
        : "memory");
    a[0] = a0; a[1] = a1; a[2] = a2; a[3] = a3;
    a[4] = a4; a[5] = a5; a[6] = a6; a[7] = a7;
}
__device__ inline void ld_x32_nw(const void* addr, u32& x_) {
    asm volatile("global_load_dword %0, %1, off" : "=&v"(x_) : "v"(addr) : "memory");
}
__device__ inline void ld_P2_nw(const float* addr, u32x4& p0, u32x4& p1) {
    asm volatile("global_load_dwordx4 %0, %2, off offset:0\n\t"
                 "global_load_dwordx4 %1, %2, off offset:16"
                 : "=&v"(p0), "=&v"(p1) : "v"(addr) : "memory");
}
__device__ inline u32 maxdw4(u32x4 a) {
    u32 m0 = a[0] > a[1] ? a[0] : a[1];
    u32 m1 = a[2] > a[3] ? a[2] : a[3];
    return m0 > m1 ? m0 : m1;
}
__device__ inline int row_ok(const u32x4 a[8]) {
    u32 m = maxdw4(a[0]);
    #pragma unroll
    for (int j = 1; j < 8; ++j) { u32 t = maxdw4(a[j]); m = t > m ? t : m; }
    return (int)(m != SENT);
}

// ---------------------------------------------------------------------------
__global__ void detect_dtype(const u16* __restrict__ emb, const int* __restrict__ xi,
                             int* __restrict__ flag) {
    float v = b2f(emb[threadIdx.x]);
    if (!(fabsf(v) <= 1.0e6f)) atomicOr(flag, 1);
    if (xi[2 * threadIdx.x + 1] != 0) atomicOr(flag, 2);
}

__global__ void precompute_P(const void* __restrict__ emb, const void* __restrict__ We,
                             const void* __restrict__ bh, float* __restrict__ P,
                             const int* __restrict__ flag) {
    const int isf32 = *flag & 1;
    int o = blockIdx.x * 256 + threadIdx.x;
    int v = o >> 10, h = o & (H_SZ - 1);
    float acc = ldf(bh, h, isf32);
    for (int e = 0; e < E_SZ; ++e)
        acc += ldf(emb, v * E_SZ + e, isf32) * ldf(We, (long)e * H_SZ + h, isf32);
    P[o] = acc;
}

// ---------------------------------------------------------------------------
// Persistent RNN — R23. 64 WGs x 256 thr. group g=blockIdx&7 (16 batches),
// wg=blockIdx>>3 owns cols [128wg,128wg+128): whf[8][8]+wof[2][8] stationary.
// Wave = K-quarter; 64(+16 duty) MFMAs/step; 4-way LDS reduce; fast-tanh;
// cross-step speculative pipeline + R19 fallback poll; lgkm-only barriers.
// ---------------------------------------------------------------------------
__global__ void __launch_bounds__(256, 1) rnn_kernel(
    const void* __restrict__ xp, const void* __restrict__ hidden,
    const void* __restrict__ Wh, const void* __restrict__ Wo,
    const void* __restrict__ bo, const float* __restrict__ P,
    u16* __restrict__ hbuf, float* __restrict__ out,
    const int* __restrict__ flag)
{
    __shared__ __align__(16) float red[12800];   // 50 KB

    const int fl    = *flag;
    const int isf32 = fl & 1;
    const int xi64  = !(fl & 2);
    const int g     = blockIdx.x & 7;
    const int wg    = blockIdx.x >> 3;
    const int col0  = wg * 128;
    const int b0    = g * 16;
    const int tid   = threadIdx.x;
    const int wave  = tid >> 6;
    const int lane  = tid & 63;
    const int lrow  = lane & 15;
    const int quad  = lane >> 4;
    const int kwave = wave * 256;

    const char* xbase = (const char*)xp;
    const int   xstep = xi64 ? 8 : 4;

    u16* hb = hbuf + g * HBUF_G;                 // 4 buffers of 16 x H bf16

    long gb = 100000L;                           // global failed-check budget

    // ---- stationary weights (cached loads, L2-warm forever) ----
    short8 whf[8][8], wof[2][8];
    #pragma unroll
    for (int kk = 0; kk < 8; ++kk) {
        const int kb = kwave + kk * 32 + quad * 8;
        #pragma unroll
        for (int j = 0; j < 8; ++j) {
            #pragma unroll
            for (int nt = 0; nt < 8; ++nt)
                whf[nt][kk][j] = (short)ldb(Wh, (long)(kb + j) * H_SZ + col0 + nt * 16 + lrow, isf32);
            wof[0][kk][j] = (short)ldb(Wo, (long)(kb + j) * V_SZ + lrow, isf32);
            wof[1][kk][j] = (short)ldb(Wo, (long)(kb + j) * V_SZ + 16 + lrow, isf32);
        }
    }

    const int bq = tid >> 4;             // batch row 0..15
    const int c0 = (tid & 15) * 8;       // 8 consecutive cols [c0, c0+8)
    const float bov0 = ldf(bo, (tid & 15) * 2, isf32);
    const float bov1 = ldf(bo, (tid & 15) * 2 + 1, isf32);

    // ---- init h_0 slice into buf0 (buf1..3 are sentinel via host memset) ----
    {
        u32x4 d;
        #pragma unroll
        for (int p = 0; p < 4; ++p) {
            u16 lo = ldb(hidden, (long)(b0 + bq) * H_SZ + col0 + c0 + 2 * p, isf32);
            u16 hi = ldb(hidden, (long)(b0 + bq) * H_SZ + col0 + c0 + 2 * p + 1, isf32);
            d[p] = (u32)lo | ((u32)hi << 16);
        }
        st_row16((u32*)(hb + bq * H_SZ + col0 + c0), d);
    }

    // ---- prologue: prime the pipeline (P[x_0], x_1, S0 @ h_0) ----
    u32x4 S0[8];
    u32x4 pu0, pu1;      // P[x_s] bits, completed at each step's head drain
    u32   xr;            // x_{s+1} value, completed at each step's head drain
    {
        long xo0 = (long)(b0 + bq) * L_SEQ;
        int xv0 = xi64 ? (int)((const long long*)xp)[xo0] : ((const int*)xp)[xo0];
        ld_P2_nw(P + (long)xv0 * H_SZ + col0 + c0, pu0, pu1);
        ld_x32_nw(xbase + (xo0 + 1) * xstep, xr);
        ld8_nw(hb + lrow * H_SZ + kwave + quad * 8, S0);
    }

    for (int s = 0; s < L_SEQ; ++s) {
        const u16* hc = hb + (s & 3) * (16 * H_SZ);          // h_s
        u16* hn       = hb + ((s + 1) & 3) * (16 * H_SZ);    // h_{s+1}
        u16* hcl      = hb + ((s + 3) & 3) * (16 * H_SZ);    // holds h_{s-1}
        const bool do_logit = (wg == (s & 7));
        const u16* ab = hc + lrow * H_SZ + kwave + quad * 8;

        // ---- head: one drain (loads issued a barrier ago) + reg-read fence ----
        VMCNT0();
        __builtin_amdgcn_sched_barrier(0);

        // ---- fast path: speculative S0 already holds fresh h_s? ----
        if (!__all(row_ok(S0))) {
            // fallback: R19's exact self-contained poll (waitcnt in-block)
            for (;;) {
                if (--gb < 0) break;             // fail fast+visible, never hang
                __builtin_amdgcn_s_sleep(2);
                ld_row16_raw(ab, S0);
                if (__all(row_ok(S0))) break;
            }
        }

        // ---- MFMA: 8 col-tiles; duty WG fuses its 2 logit tiles in-burst ----
        floatx4 acc[8] = {};
        floatx4 aL0 = {0,0,0,0}, aL1 = {0,0,0,0};
        #pragma unroll
        for (int kk = 0; kk < 8; ++kk) {
            union { u32x4 v; short8 h; } ua; ua.v = S0[kk];
            #pragma unroll
            for (int nt = 0; nt < 8; ++nt)
                acc[nt] = MFMA16x16x32(ua.h, whf[nt][kk], acc[nt]);
            if (do_logit) {
                aL0 = MFMA16x16x32(ua.h, wof[0][kk], aL0);
                aL1 = MFMA16x16x32(ua.h, wof[1][kk], aL1);
            }
        }

        if (do_logit) {
            #pragma unroll
            for (int r = 0; r < 4; ++r) {
                red[10240 + wave * 640 +       (quad * 4 + r) * 20 + lrow] = aL0[r];
                red[10240 + wave * 640 + 320 + (quad * 4 + r) * 20 + lrow] = aL1[r];
            }
        }
        // C layout: col = lane&15, row = quad*4 + r
        #pragma unroll
        for (int nt = 0; nt < 8; ++nt)
            #pragma unroll
            for (int r = 0; r < 4; ++r)
                red[wave * 2560 + nt * 320 + (quad * 4 + r) * 20 + lrow] = acc[nt][r];
        bar_lgkm();   // sync-A: LDS partials visible; no vmcnt drain

        // ---- epilogue: h_{s+1} = tanh(P[x_s] + h_s @ Wh), one 16B h-store ----
        {
            const int base = (c0 >> 4) * 320 + bq * 20 + (c0 & 15);
            floatx4 s0 = {0,0,0,0}, s1 = {0,0,0,0};
            #pragma unroll
            for (int w = 0; w < 4; ++w) {
                s0 += *(const floatx4*)&red[w * 2560 + base];
                s1 += *(const floatx4*)&red[w * 2560 + base + 4];
            }
            union { u32x4 v; float f[4]; } q0, q1;
            q0.v = pu0; q1.v = pu1;            // fenced by head sched_barrier
            float h[8];
            #pragma unroll
            for (int j = 0; j < 4; ++j) h[j]     = fast_tanh(s0[j] + q0.f[j]);
            #pragma unroll
            for (int j = 0; j < 4; ++j) h[4 + j] = fast_tanh(s1[j] + q1.f[j]);
            u32x4 d;
            #pragma unroll
            for (int p = 0; p < 4; ++p)
                d[p] = (u32)f2b(h[2 * p]) | ((u32)f2b(h[2 * p + 1]) << 16);
            st_row16((u32*)(hn + bq * H_SZ + col0 + c0), d);
            if (s == L_SEQ - 1) {
                float* op = out + LOGIT_BASE + (long)(b0 + bq) * H_SZ + col0 + c0;
                ((floatx4*)op)[0] = floatx4{h[0], h[1], h[2], h[3]};
                ((floatx4*)op)[1] = floatx4{h[4], h[5], h[6], h[7]};
            }
        }
        // ---- re-sentinel own slice of buf[(s+3)&3]; not needed past L-3 ----
        if (s <= L_SEQ - 3) {
            u32x4 f = { SENT, SENT, SENT, SENT };
            st_row16((u32*)(hcl + bq * H_SZ + col0 + c0), f);
        }

        // ---- duty WG: tiny logits[s-1] reduce (partials written pre-sync-A) ----
        if (do_logit && s >= 1) {
            int v0 = (tid & 15) * 2;
            int lb = 10240 + (v0 >> 4) * 320 + bq * 20 + (v0 & 15);
            float q0 = 0.f, q1 = 0.f;
            #pragma unroll
            for (int w = 0; w < 4; ++w) {
                q0 += red[lb + w * 640];
                q1 += red[lb + w * 640 + 1];
            }
            long ob = ((long)(b0 + bq) * L_SEQ + (s - 1)) * V_SZ + v0;
            out[ob]     = q0 + bov0;
            out[ob + 1] = q1 + bov1;
        }

        // ---- step end: speculative issues for step s+1 (fly across sync-B).
        //      xr holds x_{s+1} (completed at this head). Read it, THEN
        //      re-issue xr <- x_{s+2}; pu <- P[x_{s+1}]; S0 <- h_{s+1} snap. ----
        {
            int xnv = (int)xr;                                   // x_{s+1}
            ld_P2_nw(P + (long)xnv * H_SZ + col0 + c0, pu0, pu1);
            long s2 = (s + 2 < L_SEQ) ? (s + 2) : 0;             // harmless clamp
            ld_x32_nw(xbase + ((long)(b0 + bq) * L_SEQ + s2) * xstep, xr);
            ld8_nw(hn + lrow * H_SZ + kwave + quad * 8, S0);
        }
        bar_lgkm();   // sync-B: red[] reads done before next step's writes
    }

    VMCNT0();   // retire all speculative in-flight before reg reuse below
    __builtin_amdgcn_sched_barrier(0);

    // ---- final logits t = L-1 from h_L (buf[1024&3] = buf0), WG0 of group ----
    if (wg == 0) {
        const u16* ab = hb + lrow * H_SZ + kwave + quad * 8;
        // S0 already holds a speculative h_L snapshot (issued at s=1023 end)
        if (!__all(row_ok(S0))) {
            for (;;) {
                if (--gb < 0) break;
                __builtin_amdgcn_s_sleep(2);
                ld_row16_raw(ab, S0);
                if (__all(row_ok(S0))) break;
            }
        }
        floatx4 aL0 = {0,0,0,0}, aL1 = {0,0,0,0};
        #pragma unroll
        for (int kk = 0; kk < 8; ++kk) {
            union { u32x4 v; short8 h; } ua; ua.v = S0[kk];
            aL0 = MFMA16x16x32(ua.h, wof[0][kk], aL0);
            aL1 = MFMA16x16x32(ua.h, wof[1][kk], aL1);
        }
        #pragma unroll
        for (int r = 0; r < 4; ++r) {
            red[10240 + wave * 640 +       (quad * 4 + r) * 20 + lrow] = aL0[r];
            red[10240 + wave * 640 + 320 + (quad * 4 + r) * 20 + lrow] = aL1[r];
        }
        __syncthreads();
        {
            int v0 = (tid & 15) * 2;
            int lb = 10240 + (v0 >> 4) * 320 + bq * 20 + (v0 & 15);
            float q0 = 0.f, q1 = 0.f;
            #pragma unroll
            for (int w = 0; w < 4; ++w) {
                q0 += red[lb + w * 640];
                q1 += red[lb + w * 640 + 1];
            }
            long ob = ((long)(b0 + bq) * L_SEQ + (L_SEQ - 1)) * V_SZ + v0;
            out[ob]     = q0 + bov0;
            out[ob + 1] = q1 + bov1;
        }
    }
}

// ---------------------------------------------------------------------------
extern "C" void kernel_launch(void* const* d_in, const int* in_sizes, int n_in,
                              void* d_out, int out_size, void* d_ws, size_t ws_size,
                              hipStream_t stream) {
    (void)in_sizes; (void)n_in; (void)out_size; (void)ws_size;
    const void* x      = d_in[0];
    const void* hidden = d_in[1];
    const void* emb    = d_in[2];
    const void* We     = d_in[3];
    const void* Wh     = d_in[4];
    const void* bh     = d_in[5];
    const void* Wo     = d_in[6];
    const void* bo     = d_in[7];
    float* out = (float*)d_out;

    char* ws = (char*)d_ws;
    int*   flag = (int*)(ws + FLAG_OFF);
    float* P    = (float*)(ws + P_OFF);
    u16*   hbuf = (u16*)(ws + HBUF_OFF);

    hipMemsetAsync(ws, 0, BAR_BYTES, stream);                 // dtype flag = 0
    hipMemsetAsync(ws + HBUF_OFF, 0xFF, HBUF_BYTES, stream);  // all h-bufs = sentinel

    detect_dtype<<<dim3(1), dim3(256), 0, stream>>>((const u16*)emb, (const int*)x, flag);
    precompute_P<<<dim3(128), dim3(256), 0, stream>>>(emb, We, bh, P, flag);

    rnn_kernel<<<dim3(N_BLOCKS), dim3(256), 0, stream>>>(
        x, hidden, Wh, Wo, bo, P, hbuf, out, flag);
}

// Round 12
// 3232.925 us; speedup vs baseline: 2.5396x; 1.0494x over previous
//
#include <hip/hip_runtime.h>

typedef unsigned short u16;
typedef unsigned int   u32;
typedef __attribute__((ext_vector_type(4))) float floatx4;
typedef __attribute__((ext_vector_type(4))) u32  u32x4;
typedef __attribute__((ext_vector_type(8))) short short8;

#define B_SZ  128
#define L_SEQ 1024
#define V_SZ  32
#define E_SZ  256
#define H_SZ  1024

#define N_GROUPS     8
#define WG_PER_GROUP 8                   // 8 WGs x 128 cols = 1024
#define N_BLOCKS     (N_GROUPS * WG_PER_GROUP)   // 64
#define LOGIT_BASE   (B_SZ * L_SEQ * V_SZ)

// workspace layout (bytes)
#define BAR_BYTES  8192
#define FLAG_OFF   (BAR_BYTES - 8)       // dtype flag
#define P_OFF      BAR_BYTES
#define P_BYTES    (V_SZ * H_SZ * 4)
#define HBUF_OFF   (P_OFF + P_BYTES)
#define NBUF       4                     // h_t lives in buf[t & 3]
#define HBUF_G     (NBUF * 16 * H_SZ)    // u16 elements per group
#define HBUF_BYTES (N_GROUPS * HBUF_G * 2)

// Sentinel dword = two bf16 NaNs. f2b(tanh(finite)) is in [-1,1] -> real h
// dwords are always < 0xFFFFFFFF, so freshness("all !=SENT") == max != SENT.
#define SENT 0xFFFFFFFFu

#define MFMA16x16x32(a, b, c) __builtin_amdgcn_mfma_f32_16x16x32_bf16(a, b, c, 0, 0, 0)

__device__ inline float b2f(u16 u) {
    union { unsigned i; float f; } x; x.i = ((unsigned)u) << 16; return x.f;
}
__device__ inline u16 f2b(float f) {
    unsigned u = __float_as_uint(f);
    return (u16)((u + 0x7FFFu + ((u >> 16) & 1u)) >> 16);   // RNE
}
__device__ inline float ldf(const void* p, long i, int isf32) {
    return isf32 ? ((const float*)p)[i] : b2f(((const u16*)p)[i]);
}
__device__ inline u16 ldb(const void* p, long i, int isf32) {
    return isf32 ? f2b(((const float*)p)[i]) : ((const u16*)p)[i];
}

// tanh via hw exp2 + rcp: rel err ~1e-6, swamped by bf16 h-rounding (2^-8).
// Clamp +-15: tanh(15) rounds to exactly 1.0f, matching libm saturation.
__device__ inline float fast_tanh(float x) {
    float cx = fminf(fmaxf(x, -15.f), 15.f);
    float t  = __builtin_amdgcn_exp2f(cx * 2.885390081777927f);   // e^{2x}
    return (t - 1.f) * __builtin_amdgcn_rcpf(t + 1.f);
}

// ---------------------------------------------------------------------------
// FINAL STATE (R24 = R16 verbatim, the session's best-measured kernel).
// Search ledger (do not regress):
// R11/R12: sc0-only polling read stale data -> sc0+sc1 LLC-scope ONLY.
// R8:  asm outputs must be early-clobber.
// R14/R15: incremental-MFMA-in-poll regressed -> keep the poll TIGHT.
// R16: fast_tanh + fused duty logits + cheap check -> 3216us. BEST.
// R18: probe-then-bulk regressed (+outlier) -> detect+deliver share ONE RT.
// R19: lgkm-only barriers + backoff NEUTRAL -> barrier drains immaterial.
// R21: full-K waves regressed 2.6x -> keep per-wave fan-in small.
// R22: crashed (waitcnt does not order register reads across asm blocks).
// R23: cross-step speculation neutral-worse + tail outliers (misses).
// Conclusion: per-step cost ~2.7us = store->LLC visibility + detection
// quantization + max-of-8 coupling, serialized 1024x. Batch-partitioned
// (exchange-free) alternatives are Wh-bandwidth-bound at >=2us/step.
// This is the structural floor of the forced column-partition + all-to-all
// h-exchange design; counters (MfmaUtil 3.6%) reflect chain latency, not a
// fixable utilization deficit.
// ---------------------------------------------------------------------------
__device__ inline void ld_row16_raw(const u16* abase, u32x4 a[8]) {
    u32x4 a0, a1, a2, a3, a4, a5, a6, a7;
    asm volatile(
        "global_load_dwordx4 %0, %8, off offset:0   sc0 sc1\n\t"
        "global_load_dwordx4 %1, %8, off offset:64  sc0 sc1\n\t"
        "global_load_dwordx4 %2, %8, off offset:128 sc0 sc1\n\t"
        "global_load_dwordx4 %3, %8, off offset:192 sc0 sc1\n\t"
        "global_load_dwordx4 %4, %8, off offset:256 sc0 sc1\n\t"
        "global_load_dwordx4 %5, %8, off offset:320 sc0 sc1\n\t"
        "global_load_dwordx4 %6, %8, off offset:384 sc0 sc1\n\t"
        "global_load_dwordx4 %7, %8, off offset:448 sc0 sc1\n\t"
        "s_waitcnt vmcnt(0)"
        : "=&v"(a0), "=&v"(a1), "=&v"(a2), "=&v"(a3),
          "=&v"(a4), "=&v"(a5), "=&v"(a6), "=&v"(a7)
        : "v"(abase)
        : "memory");
    a[0] = a0; a[1] = a1; a[2] = a2; a[3] = a3;
    a[4] = a4; a[5] = a5; a[6] = a6; a[7] = a7;
}
__device__ inline u32 maxdw4(u32x4 a) {
    u32 m0 = a[0] > a[1] ? a[0] : a[1];
    u32 m1 = a[2] > a[3] ? a[2] : a[3];
    return m0 > m1 ? m0 : m1;
}
__device__ inline int row_ok(const u32x4 a[8]) {
    u32 m = maxdw4(a[0]);
    #pragma unroll
    for (int j = 1; j < 8; ++j) { u32 t = maxdw4(a[j]); m = t > m ? t : m; }
    return (int)(m != SENT);
}
// Poll-load one wave's A fragments: returns when all 32 dwords/lane are
// non-sentinel wave-wide. Each poll iteration is one LLC RT; this wave only
// depends on its 2 K-range producer WGs (fan-in 2, not 8).
__device__ inline void poll_row16(const u16* abase, short8 afr[8]) {
    u32x4 av[8];
    ld_row16_raw(abase, av);
    long guard = 0;
    while (!__all(row_ok(av))) {
        if (++guard > 100000L) break;    // fail visibly + fast, never hang
        ld_row16_raw(abase, av);
    }
    union { u32x4 v; short8 s; } u;
    #pragma unroll
    for (int j = 0; j < 8; ++j) { u.v = av[j]; afr[j] = u.s; }
}
__device__ inline void st_row16(u32* p, u32x4 d) {
    asm volatile("global_store_dwordx4 %0, %1, off sc0 sc1" :: "v"(p), "v"(d) : "memory");
}

// ---------------------------------------------------------------------------
__global__ void detect_dtype(const u16* __restrict__ emb, const int* __restrict__ xi,
                             int* __restrict__ flag) {
    float v = b2f(emb[threadIdx.x]);
    if (!(fabsf(v) <= 1.0e6f)) atomicOr(flag, 1);
    if (xi[2 * threadIdx.x + 1] != 0) atomicOr(flag, 2);
}

__global__ void precompute_P(const void* __restrict__ emb, const void* __restrict__ We,
                             const void* __restrict__ bh, float* __restrict__ P,
                             const int* __restrict__ flag) {
    const int isf32 = *flag & 1;
    int o = blockIdx.x * 256 + threadIdx.x;
    int v = o >> 10, h = o & (H_SZ - 1);
    float acc = ldf(bh, h, isf32);
    for (int e = 0; e < E_SZ; ++e)
        acc += ldf(emb, v * E_SZ + e, isf32) * ldf(We, (long)e * H_SZ + h, isf32);
    P[o] = acc;
}

// ---------------------------------------------------------------------------
// Persistent RNN — R24 (= R16). 64 WGs x 256 thr. group g=blockIdx&7 (16
// batches), wg=blockIdx>>3 owns cols [128wg,128wg+128): whf[8][8] stationary
// in VGPRs. Wave = K-quarter; 64 MFMAs/wave/step (+16 logit MFMAs on duty WG,
// fused into the same burst); 4-way LDS reduce (b-stride 20); fast-tanh
// epilogue; 4 rotating LLC h-buffers, freshness = data != sentinel.
// ---------------------------------------------------------------------------
__global__ void __launch_bounds__(256, 1) rnn_kernel(
    const void* __restrict__ xp, const void* __restrict__ hidden,
    const void* __restrict__ Wh, const void* __restrict__ Wo,
    const void* __restrict__ bo, const float* __restrict__ P,
    u16* __restrict__ hbuf, float* __restrict__ out,
    const int* __restrict__ flag)
{
    __shared__ __align__(16) float red[12800];   // 50 KB

    const int fl    = *flag;
    const int isf32 = fl & 1;
    const int xi64  = !(fl & 2);
    const int g     = blockIdx.x & 7;
    const int wg    = blockIdx.x >> 3;
    const int col0  = wg * 128;
    const int b0    = g * 16;
    const int tid   = threadIdx.x;
    const int wave  = tid >> 6;
    const int lane  = tid & 63;
    const int lrow  = lane & 15;
    const int quad  = lane >> 4;
    const int kwave = wave * 256;

    const int* x32       = (const int*)xp;
    const long long* x64 = (const long long*)xp;

    u16* hb = hbuf + g * HBUF_G;                 // 4 buffers of 16 x H bf16

    // ---- stationary weights (cached loads, L2-warm forever) ----
    short8 whf[8][8], wof[2][8];
    #pragma unroll
    for (int kk = 0; kk < 8; ++kk) {
        const int kb = kwave + kk * 32 + quad * 8;
        #pragma unroll
        for (int j = 0; j < 8; ++j) {
            #pragma unroll
            for (int nt = 0; nt < 8; ++nt)
                whf[nt][kk][j] = (short)ldb(Wh, (long)(kb + j) * H_SZ + col0 + nt * 16 + lrow, isf32);
            wof[0][kk][j] = (short)ldb(Wo, (long)(kb + j) * V_SZ + lrow, isf32);
            wof[1][kk][j] = (short)ldb(Wo, (long)(kb + j) * V_SZ + 16 + lrow, isf32);
        }
    }

    const int bq = tid >> 4;             // batch row 0..15
    const int c0 = (tid & 15) * 8;       // 8 consecutive cols [c0, c0+8)
    const float bov0 = ldf(bo, (tid & 15) * 2, isf32);
    const float bov1 = ldf(bo, (tid & 15) * 2 + 1, isf32);

    // ---- init h_0 slice into buf0 (buf1..3 are sentinel via host memset) ----
    {
        u32x4 d;
        #pragma unroll
        for (int p = 0; p < 4; ++p) {
            u16 lo = ldb(hidden, (long)(b0 + bq) * H_SZ + col0 + c0 + 2 * p, isf32);
            u16 hi = ldb(hidden, (long)(b0 + bq) * H_SZ + col0 + c0 + 2 * p + 1, isf32);
            d[p] = (u32)lo | ((u32)hi << 16);
        }
        st_row16((u32*)(hb + bq * H_SZ + col0 + c0), d);
    }

    for (int s = 0; s < L_SEQ; ++s) {
        const u16* hc = hb + (s & 3) * (16 * H_SZ);          // h_s
        u16* hn       = hb + ((s + 1) & 3) * (16 * H_SZ);    // h_{s+1}
        u16* hcl      = hb + ((s + 3) & 3) * (16 * H_SZ);    // future h_{s+3}
        const bool do_logit = (wg == (s & 7));

        // ---- prefetch x, P (independent of h — issued before the poll) ----
        long xoff = (long)(b0 + bq) * L_SEQ + s;
        int xv = xi64 ? (int)x64[xoff] : x32[xoff];
        const floatx4* pp = (const floatx4*)(P + (long)xv * H_SZ + col0 + c0);
        floatx4 pv0 = pp[0], pv1 = pp[1];

        // ---- poll-load A frags: ONE LLC RT detects + delivers fresh h_s ----
        short8 afr[8];
        poll_row16(hc + lrow * H_SZ + kwave + quad * 8, afr);

        // ---- MFMA: 8 col-tiles; duty WG fuses its 2 logit tiles in-burst ----
        floatx4 acc[8] = {};
        #pragma unroll
        for (int kk = 0; kk < 8; ++kk)
            #pragma unroll
            for (int nt = 0; nt < 8; ++nt)
                acc[nt] = MFMA16x16x32(afr[kk], whf[nt][kk], acc[nt]);
        if (do_logit) {
            floatx4 aL0 = {0,0,0,0}, aL1 = {0,0,0,0};
            #pragma unroll
            for (int kk = 0; kk < 8; ++kk) {
                aL0 = MFMA16x16x32(afr[kk], wof[0][kk], aL0);
                aL1 = MFMA16x16x32(afr[kk], wof[1][kk], aL1);
            }
            #pragma unroll
            for (int r = 0; r < 4; ++r) {
                red[10240 + wave * 640 +       (quad * 4 + r) * 20 + lrow] = aL0[r];
                red[10240 + wave * 640 + 320 + (quad * 4 + r) * 20 + lrow] = aL1[r];
            }
        }

        // C layout: col = lane&15, row = quad*4 + r
        #pragma unroll
        for (int nt = 0; nt < 8; ++nt)
            #pragma unroll
            for (int r = 0; r < 4; ++r)
                red[wave * 2560 + nt * 320 + (quad * 4 + r) * 20 + lrow] = acc[nt][r];
        __syncthreads();   // sync-A: all waves' partials (+logit partials) in

        // ---- epilogue: h_{s+1} = tanh(P[x_s] + h_s @ Wh), one 16B h-store ----
        {
            const int base = (c0 >> 4) * 320 + bq * 20 + (c0 & 15);
            floatx4 s0 = {0,0,0,0}, s1 = {0,0,0,0};
            #pragma unroll
            for (int w = 0; w < 4; ++w) {
                s0 += *(const floatx4*)&red[w * 2560 + base];
                s1 += *(const floatx4*)&red[w * 2560 + base + 4];
            }
            float h[8];
            #pragma unroll
            for (int j = 0; j < 4; ++j) h[j]     = fast_tanh(s0[j] + pv0[j]);
            #pragma unroll
            for (int j = 0; j < 4; ++j) h[4 + j] = fast_tanh(s1[j] + pv1[j]);
            u32x4 d;
            #pragma unroll
            for (int p = 0; p < 4; ++p)
                d[p] = (u32)f2b(h[2 * p]) | ((u32)f2b(h[2 * p + 1]) << 16);
            st_row16((u32*)(hn + bq * H_SZ + col0 + c0), d);
            if (s == L_SEQ - 1) {
                float* op = out + LOGIT_BASE + (long)(b0 + bq) * H_SZ + col0 + c0;
                ((floatx4*)op)[0] = floatx4{h[0], h[1], h[2], h[3]};
                ((floatx4*)op)[1] = floatx4{h[4], h[5], h[6], h[7]};
            }
        }
        // ---- re-sentinel own slice of buf[(s+3)&3] (safe: see header proof) ----
        {
            u32x4 f = { SENT, SENT, SENT, SENT };
            st_row16((u32*)(hcl + bq * H_SZ + col0 + c0), f);
        }

        // ---- duty WG: tiny logits[s-1] reduce (partials written pre-sync-A;
        //      reads ordered vs next step's writes by sync-B — no extra sync) ----
        if (do_logit && s >= 1) {
            int v0 = (tid & 15) * 2;
            int lb = 10240 + (v0 >> 4) * 320 + bq * 20 + (v0 & 15);
            float q0 = 0.f, q1 = 0.f;
            #pragma unroll
            for (int w = 0; w < 4; ++w) {
                q0 += red[lb + w * 640];
                q1 += red[lb + w * 640 + 1];
            }
            long ob = ((long)(b0 + bq) * L_SEQ + (s - 1)) * V_SZ + v0;
            out[ob]     = q0 + bov0;
            out[ob + 1] = q1 + bov1;
        }
        __syncthreads();   // sync-B: red[] reads done before next step's writes
    }

    // ---- final logits t = L-1 from h_L (buf[1024&3] = buf0), WG0 of group ----
    if (wg == 0) {
        short8 afr[8];
        poll_row16(hb + lrow * H_SZ + kwave + quad * 8, afr);
        floatx4 aL0 = {0,0,0,0}, aL1 = {0,0,0,0};
        #pragma unroll
        for (int kk = 0; kk < 8; ++kk) {
            aL0 = MFMA16x16x32(afr[kk], wof[0][kk], aL0);
            aL1 = MFMA16x16x32(afr[kk], wof[1][kk], aL1);
        }
        #pragma unroll
        for (int r = 0; r < 4; ++r) {
            red[10240 + wave * 640 +       (quad * 4 + r) * 20 + lrow] = aL0[r];
            red[10240 + wave * 640 + 320 + (quad * 4 + r) * 20 + lrow] = aL1[r];
        }
        __syncthreads();
        {
            int v0 = (tid & 15) * 2;
            int lb = 10240 + (v0 >> 4) * 320 + bq * 20 + (v0 & 15);
            float q0 = 0.f, q1 = 0.f;
            #pragma unroll
            for (int w = 0; w < 4; ++w) {
                q0 += red[lb + w * 640];
                q1 += red[lb + w * 640 + 1];
            }
            long ob = ((long)(b0 + bq) * L_SEQ + (L_SEQ - 1)) * V_SZ + v0;
            out[ob]     = q0 + bov0;
            out[ob + 1] = q1 + bov1;
        }
    }
}

// ---------------------------------------------------------------------------
extern "C" void kernel_launch(void* const* d_in, const int* in_sizes, int n_in,
                              void* d_out, int out_size, void* d_ws, size_t ws_size,
                              hipStream_t stream) {
    (void)in_sizes; (void)n_in; (void)out_size; (void)ws_size;
    const void* x      = d_in[0];
    const void* hidden = d_in[1];
    const void* emb    = d_in[2];
    const void* We     = d_in[3];
    const void* Wh     = d_in[4];
    const void* bh     = d_in[5];
    const void* Wo     = d_in[6];
    const void* bo     = d_in[7];
    float* out = (float*)d_out;

    char* ws = (char*)d_ws;
    int*   flag = (int*)(ws + FLAG_OFF);
    float* P    = (float*)(ws + P_OFF);
    u16*   hbuf = (u16*)(ws + HBUF_OFF);

    hipMemsetAsync(ws, 0, BAR_BYTES, stream);                 // dtype flag = 0
    hipMemsetAsync(ws + HBUF_OFF, 0xFF, HBUF_BYTES, stream);  // all h-bufs = sentinel

    detect_dtype<<<dim3(1), dim3(256), 0, stream>>>((const u16*)emb, (const int*)x, flag);
    precompute_P<<<dim3(128), dim3(256), 0, stream>>>(emb, We, bh, P, flag);

    rnn_kernel<<<dim3(N_BLOCKS), dim3(256), 0, stream>>>(
        x, hidden, Wh, Wo, bo, P, hbuf, out, flag);
}